// Round 15
// baseline (154.396 us; speedup 1.0000x reference)
//
#include <hip/hip_runtime.h>
#include <hip/hip_bf16.h>
#include <cmath>

// x: [B=4,S=2,P=1024,D=1024] f32; W_{K,Q,V}: [S,I=16,H=64,D] f32; W_O: [S,D,I*H] f32
// out: [B,S,P,D] f32
#define C_B 4
#define C_S 2
#define C_P 1024
#define C_D 1024
#define C_I 16
#define C_H 64

typedef unsigned short u16;
typedef unsigned int u32;
typedef __attribute__((ext_vector_type(8))) short short8;
typedef __attribute__((ext_vector_type(8))) __bf16 bf16x8;
typedef __attribute__((ext_vector_type(4))) float f32x4;
typedef __attribute__((ext_vector_type(16))) float f32x16;
typedef __attribute__((ext_vector_type(4))) u32 u32x4;

__device__ __forceinline__ u16 f2bf(float f) {
  union { float f; unsigned u; } c; c.f = f;
  unsigned u = c.u;
  u += 0x7fffu + ((u >> 16) & 1u);   // RNE
  return (u16)(u >> 16);
}

__device__ __forceinline__ u32 cvtpk_bf16(float lo, float hi) {
  u32 r;
  asm("v_cvt_pk_bf16_f32 %0, %1, %2" : "=v"(r) : "v"(lo), "v"(hi));
  return r;
}

// hardware 2^x (v_exp_f32 IS exp2 on gfx9xx)
__device__ __forceinline__ float fexp2(float x) {
  return __builtin_amdgcn_exp2f(x);
}

__device__ __forceinline__ f32x4 mfma16(short8 a, short8 b, f32x4 c) {
  return __builtin_amdgcn_mfma_f32_16x16x32_bf16(
      __builtin_bit_cast(bf16x8, a), __builtin_bit_cast(bf16x8, b), c, 0, 0, 0);
}

__device__ __forceinline__ f32x16 mfma32(short8 a, short8 b, f32x16 c) {
  return __builtin_amdgcn_mfma_f32_32x32x16_bf16(
      __builtin_bit_cast(bf16x8, a), __builtin_bit_cast(bf16x8, b), c, 0, 0, 0);
}

__device__ __forceinline__ void load_lds16(const u16* g, u16* l) {
  __builtin_amdgcn_global_load_lds(
      (const __attribute__((address_space(1))) void*)g,
      (__attribute__((address_space(3))) void*)l, 16, 0, 0);
}

// ---------------- fp32 -> bf16 convert: all 5 tensors, one launch ----------------
__global__ void cvt_all(const float* __restrict__ x,
                        const float* __restrict__ wq, const float* __restrict__ wk,
                        const float* __restrict__ wvp, const float* __restrict__ wo,
                        u16* __restrict__ xbf, u16* __restrict__ wall,
                        u16* __restrict__ wob) {
  const int b = blockIdx.x;
  if (b < 2048) {
    int i = b * 256 + threadIdx.x;
    const int n4 = (C_B * C_S * C_P * C_D) / 4, stride = 2048 * 256;
    for (; i < n4; i += stride) {
      float4 v = reinterpret_cast<const float4*>(x)[i];
      ushort4 o;
      o.x = f2bf(v.x); o.y = f2bf(v.y); o.z = f2bf(v.z); o.w = f2bf(v.w);
      reinterpret_cast<ushort4*>(xbf)[i] = o;
    }
  } else {
    const int j = b - 2048;
    const int t = j >> 9;
    const float* src = (t == 0) ? wq : (t == 1) ? wk : (t == 2) ? wvp : wo;
    int i = (j & 511) * 256 + threadIdx.x;
    const int stride = 512 * 256;
    for (; i < 524288; i += stride) {
      float4 v = reinterpret_cast<const float4*>(src)[i];
      ushort4 o;
      o.x = f2bf(v.x); o.y = f2bf(v.y); o.z = f2bf(v.z); o.w = f2bf(v.w);
      if (t < 3) {
        int s = i >> 18;
        int rem = i & 262143;
        reinterpret_cast<ushort4*>(wall)[s * 786432 + t * 262144 + rem] = o;
      } else {
        reinterpret_cast<ushort4*>(wob)[i] = o;
      }
    }
  }
}

// ---------------- GEMM-BT (R8/R9-proven): 256x128 tile, BK=64, counted dbuf --
// C[M=1024, N] = A[bs] * B[s]^T, K=1024. 512 thr = 8 waves (2M x 4N), wave =
// 128x32. LDS 96 KiB (A dbuf 2x32K + B dbuf 2x16K), T2 swizzle via pre-swizzled
// global source. Schedule: b1 -> STAGE(t+1) -> vmcnt(6) -> b2 -> 4x{12 ds_read,
// setprio, 8 mfma16}; never drains prefetch mid-loop. 2 blocks/CU.
// MODE 3 (fused QKV, N=3072, grid 768): t3=by>>3; Q scaled 0.125*log2e;
//   Q,K -> [head][p][h]; V -> [head][h][p] via swizzled LDS-transpose epilogue.
// MODE 2 (out-proj, N=1024, grid 256): f32 [bs][p][n].
template<int MODE>
__global__ __launch_bounds__(512, 2)
void gemm_bt(const u16* __restrict__ A, const u16* __restrict__ Bm, void* __restrict__ C) {
  __shared__ __align__(16) u16 lds[49152];   // A: [0,32768) u16; B: [32768,49152)
  const int tid = threadIdx.x;
  const int lane = tid & 63;
  const int wv = tid >> 6;
  const int wr = wv >> 2, wc = wv & 3;       // 2M x 4N waves
  const int lr = lane & 15, lg = lane >> 4;

  // T1 bijective XCD swizzle (nwg % 8 == 0)
  const int h = (int)blockIdx.x;
  const int lid = (MODE == 3) ? ((h & 7) * 96 + (h >> 3)) : ((h & 7) * 32 + (h >> 3));
  const int bsi = (MODE == 3) ? (lid / 96) : (lid >> 5);
  const int r2  = (MODE == 3) ? (lid % 96) : (lid & 31);
  const int by = r2 >> 2, bx = r2 & 3;
  const int m0 = bx * 256, n0 = by * 128;

  const u16* Ab = A + (size_t)bsi * (C_P * C_D);
  const u16* Bb = Bm + (size_t)(bsi & 1) * (MODE == 3 ? 3 * 1048576 : 1048576);
  f32x4 acc[8][2] = {};

#define STAGE(T, BUF)                                                           \
  {                                                                             \
    const int kof = (T) * 64;                                                   \
    _Pragma("unroll")                                                           \
    for (int i = 0; i < 6; ++i) {                                               \
      int cid = tid + i * 512;                                                  \
      if (i < 4) {                                                              \
        int row = cid >> 3, c8 = (cid & 7) ^ (row & 7);                         \
        load_lds16(Ab + (size_t)(m0 + row) * 1024 + kof + c8 * 8,               \
                   lds + (BUF) * 16384 + cid * 8);                              \
      } else {                                                                  \
        int c2 = cid - 2048;                                                    \
        int row = c2 >> 3, c8 = (c2 & 7) ^ (row & 7);                           \
        load_lds16(Bb + (size_t)(n0 + row) * 1024 + kof + c8 * 8,               \
                   lds + 32768 + (BUF) * 8192 + c2 * 8);                        \
      }                                                                         \
    }                                                                           \
  }

  STAGE(0, 0)

  for (int t = 0; t < 16; ++t) {
    const int bbuf = t & 1;
    __builtin_amdgcn_s_barrier();            // b1: all waves done reading buf^1
    if (t < 15) {
      STAGE(t + 1, bbuf ^ 1)
      asm volatile("s_waitcnt vmcnt(6)" ::: "memory");   // tile-t (mine) landed
    } else {
      asm volatile("s_waitcnt vmcnt(0)" ::: "memory");
    }
    __builtin_amdgcn_s_barrier();            // b2: tile-t landed for ALL waves

    const char* Als = (const char*)lds + bbuf * 32768;
    const char* Bls = (const char*)lds + 65536 + bbuf * 16384;
#pragma unroll
    for (int p = 0; p < 4; ++p) {
      short8 af[2][2], bfr[2][2];
#pragma unroll
      for (int m2 = 0; m2 < 2; ++m2)
#pragma unroll
        for (int ks = 0; ks < 2; ++ks) {
          int row = wr * 128 + (p * 2 + m2) * 16 + lr;
          af[m2][ks] = *reinterpret_cast<const short8*>(
              Als + row * 128 + (((ks << 6) | (lg << 4)) ^ ((row & 7) << 4)));
        }
#pragma unroll
      for (int nf = 0; nf < 2; ++nf)
#pragma unroll
        for (int ks = 0; ks < 2; ++ks) {
          int row = wc * 32 + nf * 16 + lr;
          bfr[nf][ks] = *reinterpret_cast<const short8*>(
              Bls + row * 128 + (((ks << 6) | (lg << 4)) ^ ((row & 7) << 4)));
        }
      __builtin_amdgcn_s_setprio(1);
#pragma unroll
      for (int m2 = 0; m2 < 2; ++m2)
#pragma unroll
        for (int nf = 0; nf < 2; ++nf)
#pragma unroll
          for (int ks = 0; ks < 2; ++ks)
            acc[p * 2 + m2][nf] = mfma16(af[m2][ks], bfr[nf][ks], acc[p * 2 + m2][nf]);
      __builtin_amdgcn_s_setprio(0);
    }
  }
#undef STAGE

  // ---------------- epilogue ----------------
  if (MODE == 2) {
    float* dst = (float*)C + (size_t)bsi * (C_P * C_D);
#pragma unroll
    for (int mf = 0; mf < 8; ++mf)
#pragma unroll
      for (int nf = 0; nf < 2; ++nf)
#pragma unroll
        for (int r = 0; r < 4; ++r) {
          int p = m0 + wr * 128 + mf * 16 + lg * 4 + r;
          int col = n0 + wc * 32 + nf * 16 + lr;
          dst[(size_t)p * C_D + col] = acc[mf][nf][r];
        }
  } else {
    const int t3 = by >> 3;                   // 0=Q 1=K 2=V (block-uniform)
    if (t3 < 2) {
      u16* dst = (u16*)C + (size_t)t3 * 8388608;
      const float scl = (t3 == 0) ? 0.18033688f : 1.0f;   // 0.125*log2(e)
#pragma unroll
      for (int mf = 0; mf < 8; ++mf)
#pragma unroll
        for (int nf = 0; nf < 2; ++nf)
#pragma unroll
          for (int r = 0; r < 4; ++r) {
            int p = m0 + wr * 128 + mf * 16 + lg * 4 + r;
            int cg = (by & 7) * 128 + wc * 32 + nf * 16 + lr;
            dst[(size_t)(bsi * C_I + (cg >> 6)) * 65536 + (size_t)p * C_H + (cg & 63)] =
                f2bf(acc[mf][nf][r] * scl);
          }
    } else {
      // V^T: transpose 256p x 128n tile through swizzled LDS, store 16B runs
      __syncthreads();
      char* trc = (char*)lds;                 // [nl 128][pl 256] bf16, 64 KiB
#pragma unroll
      for (int mf = 0; mf < 8; ++mf)
#pragma unroll
        for (int nf = 0; nf < 2; ++nf) {
          int nl = wc * 32 + nf * 16 + lr;
          int pl0 = wr * 128 + mf * 16 + lg * 4;
#pragma unroll
          for (int r = 0; r < 4; r += 2) {
            u32 wpk = cvtpk_bf16(acc[mf][nf][r], acc[mf][nf][r + 1]);
            *reinterpret_cast<u32*>(
                trc + nl * 512 + (((pl0 + r) * 2) ^ ((nl & 15) << 5))) = wpk;
          }
        }
      __syncthreads();
      const int nl = tid >> 2, seg = tid & 3;
      const int cg = (by & 7) * 128 + nl;
      u16* dst = (u16*)C + 2 * 8388608 +
                 (size_t)(bsi * C_I + (cg >> 6)) * 65536 + (size_t)(cg & 63) * C_P +
                 m0 + seg * 64;
#pragma unroll
      for (int j = 0; j < 8; ++j) {
        short8 v = *reinterpret_cast<const short8*>(
            trc + nl * 512 + ((seg * 128 + j * 16) ^ ((nl & 15) << 5)));
        *reinterpret_cast<short8*>(dst + j * 8) = v;
      }
    }
  }
}

// ---------------- flash attention v7: 8 waves share K/V over a 256-q band ----
// Q,K: bf16 [head][p][h] (Q pre-scaled 0.125*log2e); VT: bf16 [head][h][p];
// Z: bf16 [bs][q][i*64+h]. Softmax in log2 domain.
// grid 512 x 512 thr. head = (b&7)*16 + ((b>>3)&15) (XCD-local heads, R9-proven);
// y = b>>7 in 0..3; qg = {3,2,0,1}[y] -> presumed co-resident pairs (b, b+256)
// get (qg 3, qg 0) / (qg 2, qg 1): equal tile sums (20/20). Wave wv owns 32
// q-rows at q0w = qg*256 + wv*32; ntiles = 4qg+4. Same K/V tile now feeds 256
// q-rows (2x amortization of staging vs v6); per-wave inner loop identical.
// Loop: b1 -> ASTAGE(t+1) (2 loads/thread) -> vmcnt(2) -> b2 -> compute(t).
__global__ __launch_bounds__(512, 2)
void attn_kernel(const u16* __restrict__ Q, const u16* __restrict__ K,
                 const u16* __restrict__ VT, u16* __restrict__ Z) {
  __shared__ __align__(16) u16 Kt[2][64 * 64];
  __shared__ __align__(16) u16 Vt[2][64 * 64];
  const int tid = threadIdx.x;
  const int lane = tid & 63, wv = tid >> 6;
  const int l31 = lane & 31, l5 = lane >> 5;
  const int b = (int)blockIdx.x;
  const int head = (b & 7) * 16 + ((b >> 3) & 15);
  const int y = b >> 7;                        // 0..3
  const int qg = (0x1023 >> (y * 4)) & 15;     // {3,2,0,1}[y]
  const int bs = head >> 4, ih = head & 15;
  const int q0w = qg * 256 + wv * 32;
  const u16* Qh = Q + (size_t)head * (C_P * C_H);
  const u16* Kh = K + (size_t)head * (C_P * C_H);
  const u16* Vh = VT + (size_t)head * (C_P * C_H);
  const int ntiles = 4 * qg + 4;
  const int myq = q0w + l31;
  const int swz = (l31 & 7) << 4;

  short8 qf[4];
#pragma unroll
  for (int hk = 0; hk < 4; ++hk)
    qf[hk] = *reinterpret_cast<const short8*>(
        &Qh[(size_t)(q0w + l31) * C_H + hk * 16 + l5 * 8]);

  f32x16 zacc[2] = {};
  float mrun = -INFINITY, lrun = 0.f;

  // 512 threads: 1 K-chunk + 1 V-chunk per thread per tile (512 x 16B each)
#define ASTAGE(t, buf)                                                          \
  {                                                                             \
    int r = tid >> 3;                                                           \
    int sc = (tid & 7) ^ (r & 7);                                               \
    load_lds16(Kh + (size_t)((t) * 64 + r) * C_H + sc * 8, &Kt[buf][tid * 8]);  \
    load_lds16(Vh + (size_t)r * C_P + (t) * 64 + sc * 8, &Vt[buf][tid * 8]);    \
  }

  ASTAGE(0, 0)

  for (int t = 0; t < ntiles; ++t) {
    const int cur = t & 1;
    __builtin_amdgcn_s_barrier();            // b1: all waves done reading buf cur^1
    if (t + 1 < ntiles) {
      ASTAGE(t + 1, cur ^ 1)
      asm volatile("s_waitcnt vmcnt(2)" ::: "memory");   // stage(t) (mine) landed
    } else {
      asm volatile("s_waitcnt vmcnt(0)" ::: "memory");
    }
    __builtin_amdgcn_s_barrier();            // b2: stage(t) landed for ALL waves

    if (t * 64 <= q0w + 31) {                // skip fully-masked tiles
      const char* Kc = (const char*)Kt[cur];
      f32x16 sA[2];
      __builtin_amdgcn_s_setprio(1);
#pragma unroll
      for (int kt2 = 0; kt2 < 2; ++kt2) {
        f32x16 acc = {};
        int rb = (kt2 * 32 + l31) * 128 + ((l5 * 16) ^ swz);
#pragma unroll
        for (int hk = 0; hk < 4; ++hk) {
          short8 kf = *reinterpret_cast<const short8*>(Kc + (rb ^ (hk * 32)));
          acc = mfma32(kf, qf[hk], acc);
        }
        sA[kt2] = acc;
      }
      __builtin_amdgcn_s_setprio(0);

      if (t * 64 + 63 > q0w) {
#pragma unroll
        for (int kt2 = 0; kt2 < 2; ++kt2)
#pragma unroll
          for (int r = 0; r < 16; ++r) {
            int kv = t * 64 + kt2 * 32 + (r & 3) + 8 * (r >> 2) + 4 * l5;
            if (kv > myq) sA[kt2][r] = -1.8033688e9f;
          }
      }

      float tmax = sA[0][0];
#pragma unroll
      for (int r = 1; r < 16; ++r) tmax = fmaxf(tmax, sA[0][r]);
#pragma unroll
      for (int r = 0; r < 16; ++r) tmax = fmaxf(tmax, sA[1][r]);
      tmax = fmaxf(tmax, __shfl_xor(tmax, 32, 64));
      if (!__all(tmax - mrun <= 11.5416f)) {   // defer-max (THR = 8*log2e)
        float mnew = fmaxf(mrun, tmax);
        float scal = fexp2(mrun - mnew);
        mrun = mnew;
        lrun *= scal;
#pragma unroll
        for (int r = 0; r < 16; ++r) {
          float sc = __shfl(scal, (r & 3) + 8 * (r >> 2) + 4 * l5, 64);
          zacc[0][r] *= sc;
          zacc[1][r] *= sc;
        }
      }
      float rsum = 0.f;
#pragma unroll
      for (int kt2 = 0; kt2 < 2; ++kt2)
#pragma unroll
        for (int r = 0; r < 16; ++r) {
          float e = fexp2(sA[kt2][r] - mrun);
          sA[kt2][r] = e;
          rsum += e;
        }
      rsum += __shfl_xor(rsum, 32, 64);
      lrun += rsum;

      short8 pa[4];
#pragma unroll
      for (int kt2 = 0; kt2 < 2; ++kt2) {
        u32 W[8];
#pragma unroll
        for (int i2 = 0; i2 < 8; ++i2)
          W[i2] = cvtpk_bf16(sA[kt2][2 * i2], sA[kt2][2 * i2 + 1]);
#pragma unroll
        for (int pr = 0; pr < 4; ++pr) {
          const int a = (pr & 1) + (pr >> 1) * 4;   // 0,1,4,5
          const int b2 = a + 2;                     // 2,3,6,7
          u32 send = l5 ? W[a] : W[b2];
          u32 recv = __shfl_xor(send, 32, 64);
          u32 na = l5 ? recv : W[a];
          u32 nb = l5 ? W[b2] : recv;
          W[a] = na; W[b2] = nb;
        }
        u32x4 f0 = {W[0], W[1], W[2], W[3]};
        u32x4 f1 = {W[4], W[5], W[6], W[7]};
        pa[kt2 * 2 + 0] = __builtin_bit_cast(short8, f0);
        pa[kt2 * 2 + 1] = __builtin_bit_cast(short8, f1);
      }

      const char* Vc = (const char*)Vt[cur];
      __builtin_amdgcn_s_setprio(1);
#pragma unroll
      for (int kt = 0; kt < 4; ++kt)
#pragma unroll
        for (int ht = 0; ht < 2; ++ht) {
          int row = ht * 32 + l31;
          int vb = row * 128 + (((kt * 32) | (l5 * 16)) ^ ((row & 7) << 4));
          short8 vf = *reinterpret_cast<const short8*>(Vc + vb);
          zacc[ht] = mfma32(pa[kt], vf, zacc[ht]);
        }
      __builtin_amdgcn_s_setprio(0);
    }
  }

  float inv = 1.0f / lrun;
  u16* Zb = Z + (size_t)bs * (C_P * C_I * C_H) + ih * C_H;
#pragma unroll
  for (int r = 0; r < 16; ++r) {
    int qloc = (r & 3) + 8 * (r >> 2) + 4 * l5;
    float iv = __shfl(inv, qloc, 64);
    size_t rowo = (size_t)(q0w + qloc) * (C_I * C_H);
    Zb[rowo + l31]      = f2bf(zacc[0][r] * iv);
    Zb[rowo + 32 + l31] = f2bf(zacc[1][r] * iv);
  }
#undef ASTAGE
}

// ---------------- launch ----------------
extern "C" void kernel_launch(void* const* d_in, const int* in_sizes, int n_in,
                              void* d_out, int out_size, void* d_ws, size_t ws_size,
                              hipStream_t stream) {
  const float* x  = (const float*)d_in[0];
  const float* wk = (const float*)d_in[1];
  const float* wq = (const float*)d_in[2];
  const float* wv = (const float*)d_in[3];
  const float* wo = (const float*)d_in[4];

  // ws carve (bytes), total exactly 80 MiB:
  // xbf 0..16M | wall 16M..28.6M ([s][3][1024][1024] bf16) | wob ..32M |
  // qws 32M..48M | kws ..64M | vtw ..80M.  z aliases xbf.
  char* w = (char*)d_ws;
  u16* xbf  = (u16*)w;
  u16* wall = (u16*)(w + 16777216);
  u16* wob  = (u16*)(w + 29360128);
  u16* qws  = (u16*)(w + 33554432);
  u16* zws  = xbf;   // alias: x dead after QKV GEMM
  u16* kws  = qws + 8388608;
  u16* vtw  = kws + 8388608;

  cvt_all<<<4096, 256, 0, stream>>>(x, wq, wk, wv, wo, xbf, wall, wob);

  gemm_bt<3><<<768, 512, 0, stream>>>(xbf, wall, qws);   // fused QKV (R8-proven)

  attn_kernel<<<512, 512, 0, stream>>>(qws, kws, vtw, zws);

  gemm_bt<2><<<256, 512, 0, stream>>>(zws, wob, (float*)d_out);
}

// Round 16
// 138.450 us; speedup vs baseline: 1.1152x; 1.1152x over previous
//
#include <hip/hip_runtime.h>
#include <hip/hip_bf16.h>
#include <cmath>

// x: [B=4,S=2,P=1024,D=1024] f32; W_{K,Q,V}: [S,I=16,H=64,D] f32; W_O: [S,D,I*H] f32
// out: [B,S,P,D] f32
#define C_B 4
#define C_S 2
#define C_P 1024
#define C_D 1024
#define C_I 16
#define C_H 64

typedef unsigned short u16;
typedef unsigned int u32;
typedef __attribute__((ext_vector_type(8))) short short8;
typedef __attribute__((ext_vector_type(8))) __bf16 bf16x8;
typedef __attribute__((ext_vector_type(4))) float f32x4;
typedef __attribute__((ext_vector_type(16))) float f32x16;
typedef __attribute__((ext_vector_type(4))) u32 u32x4;

__device__ __forceinline__ u16 f2bf(float f) {
  union { float f; unsigned u; } c; c.f = f;
  unsigned u = c.u;
  u += 0x7fffu + ((u >> 16) & 1u);   // RNE
  return (u16)(u >> 16);
}

__device__ __forceinline__ u32 cvtpk_bf16(float lo, float hi) {
  u32 r;
  asm("v_cvt_pk_bf16_f32 %0, %1, %2" : "=v"(r) : "v"(lo), "v"(hi));
  return r;
}

// hardware 2^x (v_exp_f32 IS exp2 on gfx9xx)
__device__ __forceinline__ float fexp2(float x) {
  return __builtin_amdgcn_exp2f(x);
}

__device__ __forceinline__ f32x4 mfma16(short8 a, short8 b, f32x4 c) {
  return __builtin_amdgcn_mfma_f32_16x16x32_bf16(
      __builtin_bit_cast(bf16x8, a), __builtin_bit_cast(bf16x8, b), c, 0, 0, 0);
}

__device__ __forceinline__ f32x16 mfma32(short8 a, short8 b, f32x16 c) {
  return __builtin_amdgcn_mfma_f32_32x32x16_bf16(
      __builtin_bit_cast(bf16x8, a), __builtin_bit_cast(bf16x8, b), c, 0, 0, 0);
}

__device__ __forceinline__ void load_lds16(const u16* g, u16* l) {
  __builtin_amdgcn_global_load_lds(
      (const __attribute__((address_space(1))) void*)g,
      (__attribute__((address_space(3))) void*)l, 16, 0, 0);
}

// ---------------- fp32 -> bf16 convert: all 5 tensors, one launch ----------------
__global__ void cvt_all(const float* __restrict__ x,
                        const float* __restrict__ wq, const float* __restrict__ wk,
                        const float* __restrict__ wvp, const float* __restrict__ wo,
                        u16* __restrict__ xbf, u16* __restrict__ wall,
                        u16* __restrict__ wob) {
  const int b = blockIdx.x;
  if (b < 2048) {
    int i = b * 256 + threadIdx.x;
    const int n4 = (C_B * C_S * C_P * C_D) / 4, stride = 2048 * 256;
    for (; i < n4; i += stride) {
      float4 v = reinterpret_cast<const float4*>(x)[i];
      ushort4 o;
      o.x = f2bf(v.x); o.y = f2bf(v.y); o.z = f2bf(v.z); o.w = f2bf(v.w);
      reinterpret_cast<ushort4*>(xbf)[i] = o;
    }
  } else {
    const int j = b - 2048;
    const int t = j >> 9;
    const float* src = (t == 0) ? wq : (t == 1) ? wk : (t == 2) ? wvp : wo;
    int i = (j & 511) * 256 + threadIdx.x;
    const int stride = 512 * 256;
    for (; i < 524288; i += stride) {
      float4 v = reinterpret_cast<const float4*>(src)[i];
      ushort4 o;
      o.x = f2bf(v.x); o.y = f2bf(v.y); o.z = f2bf(v.z); o.w = f2bf(v.w);
      if (t < 3) {
        int s = i >> 18;
        int rem = i & 262143;
        reinterpret_cast<ushort4*>(wall)[s * 786432 + t * 262144 + rem] = o;
      } else {
        reinterpret_cast<ushort4*>(wob)[i] = o;
      }
    }
  }
}

// ---------------- GEMM-BT (R8/R9-proven): 256x128 tile, BK=64, counted dbuf --
// MODE 3 (fused QKV, N=3072, grid 768): t3=by>>3; Q scaled 0.125*log2e;
//   Q,K -> [head][p][h]; V -> [head][h][p] via swizzled LDS-transpose epilogue.
// MODE 2 (out-proj, N=1024, grid 256): f32 [bs][p][n].
template<int MODE>
__global__ __launch_bounds__(512, 2)
void gemm_bt(const u16* __restrict__ A, const u16* __restrict__ Bm, void* __restrict__ C) {
  __shared__ __align__(16) u16 lds[49152];   // A: [0,32768) u16; B: [32768,49152)
  const int tid = threadIdx.x;
  const int lane = tid & 63;
  const int wv = tid >> 6;
  const int wr = wv >> 2, wc = wv & 3;       // 2M x 4N waves
  const int lr = lane & 15, lg = lane >> 4;

  // T1 bijective XCD swizzle (nwg % 8 == 0)
  const int h = (int)blockIdx.x;
  const int lid = (MODE == 3) ? ((h & 7) * 96 + (h >> 3)) : ((h & 7) * 32 + (h >> 3));
  const int bsi = (MODE == 3) ? (lid / 96) : (lid >> 5);
  const int r2  = (MODE == 3) ? (lid % 96) : (lid & 31);
  const int by = r2 >> 2, bx = r2 & 3;
  const int m0 = bx * 256, n0 = by * 128;

  const u16* Ab = A + (size_t)bsi * (C_P * C_D);
  const u16* Bb = Bm + (size_t)(bsi & 1) * (MODE == 3 ? 3 * 1048576 : 1048576);
  f32x4 acc[8][2] = {};

#define STAGE(T, BUF)                                                           \
  {                                                                             \
    const int kof = (T) * 64;                                                   \
    _Pragma("unroll")                                                           \
    for (int i = 0; i < 6; ++i) {                                               \
      int cid = tid + i * 512;                                                  \
      if (i < 4) {                                                              \
        int row = cid >> 3, c8 = (cid & 7) ^ (row & 7);                         \
        load_lds16(Ab + (size_t)(m0 + row) * 1024 + kof + c8 * 8,               \
                   lds + (BUF) * 16384 + cid * 8);                              \
      } else {                                                                  \
        int c2 = cid - 2048;                                                    \
        int row = c2 >> 3, c8 = (c2 & 7) ^ (row & 7);                           \
        load_lds16(Bb + (size_t)(n0 + row) * 1024 + kof + c8 * 8,               \
                   lds + 32768 + (BUF) * 8192 + c2 * 8);                        \
      }                                                                         \
    }                                                                           \
  }

  STAGE(0, 0)

  for (int t = 0; t < 16; ++t) {
    const int bbuf = t & 1;
    __builtin_amdgcn_s_barrier();            // b1: all waves done reading buf^1
    if (t < 15) {
      STAGE(t + 1, bbuf ^ 1)
      asm volatile("s_waitcnt vmcnt(6)" ::: "memory");   // tile-t (mine) landed
    } else {
      asm volatile("s_waitcnt vmcnt(0)" ::: "memory");
    }
    __builtin_amdgcn_s_barrier();            // b2: tile-t landed for ALL waves

    const char* Als = (const char*)lds + bbuf * 32768;
    const char* Bls = (const char*)lds + 65536 + bbuf * 16384;
#pragma unroll
    for (int p = 0; p < 4; ++p) {
      short8 af[2][2], bfr[2][2];
#pragma unroll
      for (int m2 = 0; m2 < 2; ++m2)
#pragma unroll
        for (int ks = 0; ks < 2; ++ks) {
          int row = wr * 128 + (p * 2 + m2) * 16 + lr;
          af[m2][ks] = *reinterpret_cast<const short8*>(
              Als + row * 128 + (((ks << 6) | (lg << 4)) ^ ((row & 7) << 4)));
        }
#pragma unroll
      for (int nf = 0; nf < 2; ++nf)
#pragma unroll
        for (int ks = 0; ks < 2; ++ks) {
          int row = wc * 32 + nf * 16 + lr;
          bfr[nf][ks] = *reinterpret_cast<const short8*>(
              Bls + row * 128 + (((ks << 6) | (lg << 4)) ^ ((row & 7) << 4)));
        }
      __builtin_amdgcn_s_setprio(1);
#pragma unroll
      for (int m2 = 0; m2 < 2; ++m2)
#pragma unroll
        for (int nf = 0; nf < 2; ++nf)
#pragma unroll
          for (int ks = 0; ks < 2; ++ks)
            acc[p * 2 + m2][nf] = mfma16(af[m2][ks], bfr[nf][ks], acc[p * 2 + m2][nf]);
      __builtin_amdgcn_s_setprio(0);
    }
  }
#undef STAGE

  // ---------------- epilogue ----------------
  if (MODE == 2) {
    float* dst = (float*)C + (size_t)bsi * (C_P * C_D);
#pragma unroll
    for (int mf = 0; mf < 8; ++mf)
#pragma unroll
      for (int nf = 0; nf < 2; ++nf)
#pragma unroll
        for (int r = 0; r < 4; ++r) {
          int p = m0 + wr * 128 + mf * 16 + lg * 4 + r;
          int col = n0 + wc * 32 + nf * 16 + lr;
          dst[(size_t)p * C_D + col] = acc[mf][nf][r];
        }
  } else {
    const int t3 = by >> 3;                   // 0=Q 1=K 2=V (block-uniform)
    if (t3 < 2) {
      u16* dst = (u16*)C + (size_t)t3 * 8388608;
      const float scl = (t3 == 0) ? 0.18033688f : 1.0f;   // 0.125*log2(e)
#pragma unroll
      for (int mf = 0; mf < 8; ++mf)
#pragma unroll
        for (int nf = 0; nf < 2; ++nf)
#pragma unroll
          for (int r = 0; r < 4; ++r) {
            int p = m0 + wr * 128 + mf * 16 + lg * 4 + r;
            int cg = (by & 7) * 128 + wc * 32 + nf * 16 + lr;
            dst[(size_t)(bsi * C_I + (cg >> 6)) * 65536 + (size_t)p * C_H + (cg & 63)] =
                f2bf(acc[mf][nf][r] * scl);
          }
    } else {
      // V^T: transpose 256p x 128n tile through swizzled LDS, store 16B runs
      __syncthreads();
      char* trc = (char*)lds;                 // [nl 128][pl 256] bf16, 64 KiB
#pragma unroll
      for (int mf = 0; mf < 8; ++mf)
#pragma unroll
        for (int nf = 0; nf < 2; ++nf) {
          int nl = wc * 32 + nf * 16 + lr;
          int pl0 = wr * 128 + mf * 16 + lg * 4;
#pragma unroll
          for (int r = 0; r < 4; r += 2) {
            u32 wpk = cvtpk_bf16(acc[mf][nf][r], acc[mf][nf][r + 1]);
            *reinterpret_cast<u32*>(
                trc + nl * 512 + (((pl0 + r) * 2) ^ ((nl & 15) << 5))) = wpk;
          }
        }
      __syncthreads();
      const int nl = tid >> 2, seg = tid & 3;
      const int cg = (by & 7) * 128 + nl;
      u16* dst = (u16*)C + 2 * 8388608 +
                 (size_t)(bsi * C_I + (cg >> 6)) * 65536 + (size_t)(cg & 63) * C_P +
                 m0 + seg * 64;
#pragma unroll
      for (int j = 0; j < 8; ++j) {
        short8 v = *reinterpret_cast<const short8*>(
            trc + nl * 512 + ((seg * 128 + j * 16) ^ ((nl & 15) << 5)));
        *reinterpret_cast<short8*>(dst + j * 8) = v;
      }
    }
  }
}

// ---------------- flash attention v8: v6 geometry, ONE barrier per tile ------
// Q,K: bf16 [head][p][h] (Q pre-scaled 0.125*log2e); VT: bf16 [head][h][p];
// Z: bf16 [bs][q][i*64+h]. Softmax in log2 domain.
// grid 1024 x 256 thr, 4 blocks/CU. head = (b&7)*16 + ((b>>3)&15) (XCD-local,
// R9-proven); qg balanced. Loop (wait-before-issue, single barrier):
//   vmcnt(0)  [stage(t), the only thing in flight, landed for me]
//   barrier   [=> all waves' stage(t) landed AND all done reading buf[(t+1)&1]]
//   ASTAGE(t+1) -> buf[(t+1)&1]   [write target fenced by that barrier]
//   compute(t) from buf[t&1]
// Same 1-iteration stage slack as v6, half the barriers.
__global__ __launch_bounds__(256, 4)
void attn_kernel(const u16* __restrict__ Q, const u16* __restrict__ K,
                 const u16* __restrict__ VT, u16* __restrict__ Z) {
  __shared__ __align__(16) u16 Kt[2][64 * 64];
  __shared__ __align__(16) u16 Vt[2][64 * 64];
  const int tid = threadIdx.x;
  const int lane = tid & 63, wv = tid >> 6;
  const int l31 = lane & 31, l5 = lane >> 5;
  const int b = (int)blockIdx.x;
  const int head = (b & 7) * 16 + ((b >> 3) & 15);
  const int y = b >> 7;
  const int qg = 7 - (y ^ (((y + 2) >> 2) & 1));   // balanced + longest-first
  const int bs = head >> 4, ih = head & 15;
  const int q0w = qg * 128 + wv * 32;
  const u16* Qh = Q + (size_t)head * (C_P * C_H);
  const u16* Kh = K + (size_t)head * (C_P * C_H);
  const u16* Vh = VT + (size_t)head * (C_P * C_H);
  const int ntiles = 2 * qg + 2;
  const int myq = q0w + l31;
  const int swz = (l31 & 7) << 4;

  short8 qf[4];
#pragma unroll
  for (int hk = 0; hk < 4; ++hk)
    qf[hk] = *reinterpret_cast<const short8*>(
        &Qh[(size_t)(q0w + l31) * C_H + hk * 16 + l5 * 8]);

  f32x16 zacc[2] = {};
  float mrun = -INFINITY, lrun = 0.f;

#define ASTAGE(t, buf)                                                          \
  {                                                                             \
    _Pragma("unroll")                                                           \
    for (int i = 0; i < 2; ++i) {                                               \
      int cid = wv * 128 + i * 64 + lane;                                       \
      int r = cid >> 3;                                                         \
      int sc = (cid & 7) ^ (r & 7);                                             \
      load_lds16(Kh + (size_t)((t) * 64 + r) * C_H + sc * 8, &Kt[buf][cid * 8]);\
      load_lds16(Vh + (size_t)r * C_P + (t) * 64 + sc * 8, &Vt[buf][cid * 8]);  \
    }                                                                           \
  }

  ASTAGE(0, 0)

  for (int t = 0; t < ntiles; ++t) {
    const int cur = t & 1;
    asm volatile("s_waitcnt vmcnt(0)" ::: "memory");   // stage(t) (mine) landed
    __builtin_amdgcn_s_barrier();            // all landed + prev reads retired
    if (t + 1 < ntiles) ASTAGE(t + 1, cur ^ 1)

    if (t * 64 <= q0w + 31) {                // skip fully-masked tiles
      const char* Kc = (const char*)Kt[cur];
      f32x16 sA[2];
      __builtin_amdgcn_s_setprio(1);
#pragma unroll
      for (int kt2 = 0; kt2 < 2; ++kt2) {
        f32x16 acc = {};
        int rb = (kt2 * 32 + l31) * 128 + ((l5 * 16) ^ swz);
#pragma unroll
        for (int hk = 0; hk < 4; ++hk) {
          short8 kf = *reinterpret_cast<const short8*>(Kc + (rb ^ (hk * 32)));
          acc = mfma32(kf, qf[hk], acc);
        }
        sA[kt2] = acc;
      }
      __builtin_amdgcn_s_setprio(0);

      if (t * 64 + 63 > q0w) {
#pragma unroll
        for (int kt2 = 0; kt2 < 2; ++kt2)
#pragma unroll
          for (int r = 0; r < 16; ++r) {
            int kv = t * 64 + kt2 * 32 + (r & 3) + 8 * (r >> 2) + 4 * l5;
            if (kv > myq) sA[kt2][r] = -1.8033688e9f;
          }
      }

      float tmax = sA[0][0];
#pragma unroll
      for (int r = 1; r < 16; ++r) tmax = fmaxf(tmax, sA[0][r]);
#pragma unroll
      for (int r = 0; r < 16; ++r) tmax = fmaxf(tmax, sA[1][r]);
      tmax = fmaxf(tmax, __shfl_xor(tmax, 32, 64));
      if (!__all(tmax - mrun <= 11.5416f)) {   // defer-max (THR = 8*log2e)
        float mnew = fmaxf(mrun, tmax);
        float scal = fexp2(mrun - mnew);
        mrun = mnew;
        lrun *= scal;
#pragma unroll
        for (int r = 0; r < 16; ++r) {
          float sc = __shfl(scal, (r & 3) + 8 * (r >> 2) + 4 * l5, 64);
          zacc[0][r] *= sc;
          zacc[1][r] *= sc;
        }
      }
      float rsum = 0.f;
#pragma unroll
      for (int kt2 = 0; kt2 < 2; ++kt2)
#pragma unroll
        for (int r = 0; r < 16; ++r) {
          float e = fexp2(sA[kt2][r] - mrun);
          sA[kt2][r] = e;
          rsum += e;
        }
      rsum += __shfl_xor(rsum, 32, 64);
      lrun += rsum;

      short8 pa[4];
#pragma unroll
      for (int kt2 = 0; kt2 < 2; ++kt2) {
        u32 W[8];
#pragma unroll
        for (int i2 = 0; i2 < 8; ++i2)
          W[i2] = cvtpk_bf16(sA[kt2][2 * i2], sA[kt2][2 * i2 + 1]);
#pragma unroll
        for (int pr = 0; pr < 4; ++pr) {
          const int a = (pr & 1) + (pr >> 1) * 4;   // 0,1,4,5
          const int b2 = a + 2;                     // 2,3,6,7
          u32 send = l5 ? W[a] : W[b2];
          u32 recv = __shfl_xor(send, 32, 64);
          u32 na = l5 ? recv : W[a];
          u32 nb = l5 ? W[b2] : recv;
          W[a] = na; W[b2] = nb;
        }
        u32x4 f0 = {W[0], W[1], W[2], W[3]};
        u32x4 f1 = {W[4], W[5], W[6], W[7]};
        pa[kt2 * 2 + 0] = __builtin_bit_cast(short8, f0);
        pa[kt2 * 2 + 1] = __builtin_bit_cast(short8, f1);
      }

      const char* Vc = (const char*)Vt[cur];
      __builtin_amdgcn_s_setprio(1);
#pragma unroll
      for (int kt = 0; kt < 4; ++kt)
#pragma unroll
        for (int ht = 0; ht < 2; ++ht) {
          int row = ht * 32 + l31;
          int vb = row * 128 + (((kt * 32) | (l5 * 16)) ^ ((row & 7) << 4));
          short8 vf = *reinterpret_cast<const short8*>(Vc + vb);
          zacc[ht] = mfma32(pa[kt], vf, zacc[ht]);
        }
      __builtin_amdgcn_s_setprio(0);
    }
  }

  float inv = 1.0f / lrun;
  u16* Zb = Z + (size_t)bs * (C_P * C_I * C_H) + ih * C_H;
#pragma unroll
  for (int r = 0; r < 16; ++r) {
    int qloc = (r & 3) + 8 * (r >> 2) + 4 * l5;
    float iv = __shfl(inv, qloc, 64);
    size_t rowo = (size_t)(q0w + qloc) * (C_I * C_H);
    Zb[rowo + l31]      = f2bf(zacc[0][r] * iv);
    Zb[rowo + 32 + l31] = f2bf(zacc[1][r] * iv);
  }
#undef ASTAGE
}

// ---------------- launch ----------------
extern "C" void kernel_launch(void* const* d_in, const int* in_sizes, int n_in,
                              void* d_out, int out_size, void* d_ws, size_t ws_size,
                              hipStream_t stream) {
  const float* x  = (const float*)d_in[0];
  const float* wk = (const float*)d_in[1];
  const float* wq = (const float*)d_in[2];
  const float* wv = (const float*)d_in[3];
  const float* wo = (const float*)d_in[4];

  // ws carve (bytes), total exactly 80 MiB:
  // xbf 0..16M | wall 16M..28.6M ([s][3][1024][1024] bf16) | wob ..32M |
  // qws 32M..48M | kws ..64M | vtw ..80M.  z aliases xbf.
  char* w = (char*)d_ws;
  u16* xbf  = (u16*)w;
  u16* wall = (u16*)(w + 16777216);
  u16* wob  = (u16*)(w + 29360128);
  u16* qws  = (u16*)(w + 33554432);
  u16* zws  = xbf;   // alias: x dead after QKV GEMM
  u16* kws  = qws + 8388608;
  u16* vtw  = kws + 8388608;

  cvt_all<<<4096, 256, 0, stream>>>(x, wq, wk, wv, wo, xbf, wall, wob);

  gemm_bt<3><<<768, 512, 0, stream>>>(xbf, wall, qws);   // fused QKV (R8-proven)

  attn_kernel<<<1024, 256, 0, stream>>>(qws, kws, vtw, zws);

  gemm_bt<2><<<256, 512, 0, stream>>>(zws, wob, (float*)d_out);
}